// Round 5
// baseline (146.884 us; speedup 1.0000x reference)
//
#include <hip/hip_runtime.h>
#include <math.h>

// Distral per-task MLP: 32769 heads, h = relu(W1[3->100] x + b1),
// p = softmax(W2[100->5] h + b2).  ~3.6 KB read/head, ~119 MB total.
//
// R5: persistent waves + per-wave double-buffered LDS-DMA.
// Measured matrix R1-R4: wide global_load_lds dwordx4 staging (R2/R3,
// ~36us) beats all scalar-dword variants (R1 48.5, R4 43.3) at equal
// line counts -> keep the DMA path, fix its phase gap.  Each wave now
// owns TWO 3648B LDS buffers and streams ~6 heads: stage head h+1
// (7 DMA instrs, incl. x/b2 via masked size-4 DMAs so vmcnt arithmetic
// is exact), s_waitcnt vmcnt(7) (drains head h's DMAs, leaves h+1's in
// flight), compute h from LDS, store.  No barriers (regions wave-
// private); ~100 KB continuously outstanding per CU.

#define N_HEADS 32769
#define HID     100
#define OUT     5

#define WAVES_PER_BLOCK 2        // 128 threads
#define NBLOCKS 2816             // 11 blocks/CU (LDS-limited) x 256 CU
#define NW      (NBLOCKS * WAVES_PER_BLOCK)   // 5632 persistent waves

#define RSTRIDE 912              // floats per buffer (3648 B, 16B-aligned)
#define OF_B1   300              // region float offsets: W1 0 | b1 300
#define OF_W2   400              //                       W2 400 | x 900 | b2 903
#define OF_X    900
#define OF_B2   903

#define GLOBAL_AS __attribute__((address_space(1)))
#define LDS_AS    __attribute__((address_space(3)))

static __device__ __forceinline__ void dma16(const void* g, void* l) {
    // 16B/lane: global (g pre-offset per lane) -> LDS (uniform base + lane*16)
    __builtin_amdgcn_global_load_lds((const GLOBAL_AS void*)g, (LDS_AS void*)l,
                                     16, 0, 0);
}
static __device__ __forceinline__ void dma4(const void* g, void* l) {
    // 4B/lane: LDS dest = uniform base + lane*4
    __builtin_amdgcn_global_load_lds((const GLOBAL_AS void*)g, (LDS_AS void*)l,
                                     4, 0, 0);
}

// exactly 7 DMA instructions per head (masks all non-empty -> vmcnt +7)
static __device__ __forceinline__ void stage_head(
    int head, int lane, float* region,
    const float* __restrict__ x,  const float* __restrict__ W1,
    const float* __restrict__ b1, const float* __restrict__ W2,
    const float* __restrict__ b2)
{
    const float* W1h = W1 + (size_t)head * 300;
    const float* b1h = b1 + (size_t)head * 100;
    const float* W2h = W2 + (size_t)head * 500;

    dma16(W1h + 4 * lane,                 region);                 // W1 f4 0..63
    if (lane < 11) dma16(W1h + 256 + 4 * lane, region + 256);      // W1 f4 64..74
    if (lane < 25) dma16(b1h + 4 * lane,  region + OF_B1);         // b1 25 f4
    dma16(W2h + 4 * lane,                 region + OF_W2);         // W2 f4 0..63
    if (lane < 61) dma16(W2h + 256 + 4 * lane, region + OF_W2 + 256); // W2 f4 64..124
    if (lane < 3)  dma4(x + (size_t)head * 3 + lane, region + OF_X);  // x: 3 dwords
    if (lane < 5)  dma4(b2 + (size_t)head * 5 + lane, region + OF_B2);// b2: 5 dwords
}

// wave64 DPP reduction step: acc += dpp(acc)   (R3-verified)
template <int CTRL, int ROW_MASK>
static __device__ __forceinline__ float dpp_add_step(float acc) {
    union { float f; int i; } in, out;
    in.f = acc;
    out.i = __builtin_amdgcn_update_dpp(0, in.i, CTRL, ROW_MASK, 0xF, false);
    return acc + out.f;
}
static __device__ __forceinline__ float wave_reduce_add(float acc) {
    acc = dpp_add_step<0x111, 0xF>(acc);  // row_shr:1
    acc = dpp_add_step<0x112, 0xF>(acc);  // row_shr:2
    acc = dpp_add_step<0x114, 0xF>(acc);  // row_shr:4
    acc = dpp_add_step<0x118, 0xF>(acc);  // row_shr:8
    acc = dpp_add_step<0x142, 0xA>(acc);  // row_bcast:15 -> rows 1,3
    acc = dpp_add_step<0x143, 0xC>(acc);  // row_bcast:31 -> rows 2,3
    union { float f; int i; } v, r;
    v.f = acc;
    r.i = __builtin_amdgcn_readlane(v.i, 63);
    return r.f;
}

__global__ __launch_bounds__(128) void distral_kernel(
    const float* __restrict__ x,
    const float* __restrict__ W1,
    const float* __restrict__ b1,
    const float* __restrict__ W2,
    const float* __restrict__ b2,
    float* __restrict__ out)
{
    __shared__ float lds[WAVES_PER_BLOCK][2][RSTRIDE];   // 14592 B

    const int lane = threadIdx.x & 63;
    const int wv   = threadIdx.x >> 6;
    const int w    = blockIdx.x * WAVES_PER_BLOCK + wv;  // 0..NW-1

    int head = w;                                        // NW <= N_HEADS
    stage_head(head, lane, &lds[wv][0][0], x, W1, b1, W2, b2);

    int buf = 0;
    for (;;) {
        const int  nh   = head + NW;
        const bool more = (nh < N_HEADS);                // wave-uniform
        const int  lh   = more ? nh : w;                 // dummy reload keeps vmcnt exact
        stage_head(lh, lane, &lds[wv][buf ^ 1][0], x, W1, b1, W2, b2);

        // drain cur head's 7 DMAs (+older store); leave next head's 7 in flight
        asm volatile("" ::: "memory");
        __builtin_amdgcn_s_waitcnt(0x0F77);              // vmcnt(7), lgkm/exp untouched
        asm volatile("" ::: "memory");

        const float* region = &lds[wv][buf][0];

        const float x0 = region[OF_X + 0];
        const float x1 = region[OF_X + 1];
        const float x2 = region[OF_X + 2];

        const bool has2 = (lane < HID - 64);             // lanes 0..35
        const int  j2   = has2 ? (lane + 64) : (HID - 1);

        float h0, h1;
        {
            const float* r = region + 3 * lane;
            h0 = fmaxf(fmaf(r[0], x0, fmaf(r[1], x1, fmaf(r[2], x2,
                       region[OF_B1 + lane]))), 0.0f);
        }
        {
            const float* r = region + 3 * j2;
            h1 = fmaxf(fmaf(r[0], x0, fmaf(r[1], x1, fmaf(r[2], x2,
                       region[OF_B1 + j2]))), 0.0f);
            h1 = has2 ? h1 : 0.0f;
        }

        float logit[OUT];
#pragma unroll
        for (int o = 0; o < OUT; ++o) {
            float p = fmaf(region[OF_W2 + o * HID + j2], h1,
                           region[OF_W2 + o * HID + lane] * h0);
            logit[o] = wave_reduce_add(p) + region[OF_B2 + o];
        }

        float m = -INFINITY;
#pragma unroll
        for (int o = 0; o < OUT; ++o) m = fmaxf(m, logit[o]);
        float e[OUT], s = 0.0f;
#pragma unroll
        for (int o = 0; o < OUT; ++o) { e[o] = __expf(logit[o] - m); s += e[o]; }
        const float inv = 1.0f / s;

        if (lane < OUT) {
            float v = (lane == 0) ? e[0]
                    : (lane == 1) ? e[1]
                    : (lane == 2) ? e[2]
                    : (lane == 3) ? e[3]
                    :               e[4];
            out[(size_t)head * OUT + lane] = v * inv;
        }

        if (!more) break;
        head = nh;
        buf ^= 1;
    }
}

extern "C" void kernel_launch(void* const* d_in, const int* in_sizes, int n_in,
                              void* d_out, int out_size, void* d_ws, size_t ws_size,
                              hipStream_t stream) {
    const float* x  = (const float*)d_in[0];
    const float* W1 = (const float*)d_in[1];
    const float* b1 = (const float*)d_in[2];
    const float* W2 = (const float*)d_in[3];
    const float* b2 = (const float*)d_in[4];
    float* out = (float*)d_out;

    distral_kernel<<<NBLOCKS, 128, 0, stream>>>(x, W1, b1, W2, b2, out);
}

// Round 6
// 142.663 us; speedup vs baseline: 1.0296x; 1.0296x over previous
//
#include <hip/hip_runtime.h>
#include <math.h>

// Distral per-task MLP: 32769 heads, h = relu(W1[3->100] x + b1),
// p = softmax(W2[100->5] h + b2).  ~3.6 KB read/head, ~119 MB total.
//
// R6: decisive test of the per-CU concurrency model.  R1-R5 all converge
// at 38-48us kernel time despite different structures -> hypothesis:
// per-CU outstanding-line limit (~64) x ~650cyc avg latency caps BW at
// ~3.4 TB/s.  The one untested lever: per-wave issue-burst depth.  Each
// wave now stages TWO ADJACENT heads (10 wide DMAs, 7.2 KB) back-to-back,
// then split-drains: vmcnt(5) -> compute head A -> vmcnt(1) -> compute
// head B.  Adjacent pairing makes each wave's W1/W2 streams contiguous
// (2.4/4 KB).  x,b2 via wave-uniform scalar path (readfirstlane).
// If neutral: structural bound confirmed.

#define N_HEADS 32769
#define HID     100
#define OUT     5

#define WAVES_PER_BLOCK 2        // 128 threads; 4 heads per block
#define HEAD_F 900               // region floats: W1 0..299 | b1 300..399 | W2 400..899
#define OF_B1  300
#define OF_W2  400

#define GLOBAL_AS __attribute__((address_space(1)))
#define LDS_AS    __attribute__((address_space(3)))

static __device__ __forceinline__ void dma16(const void* g, void* l) {
    __builtin_amdgcn_global_load_lds((const GLOBAL_AS void*)g, (LDS_AS void*)l,
                                     16, 0, 0);
}

// 5 wide DMA instructions per head (R2-verified layout)
static __device__ __forceinline__ void stage_head(
    int head, int lane, float* region,
    const float* __restrict__ W1, const float* __restrict__ b1,
    const float* __restrict__ W2)
{
    const float* W1h = W1 + (size_t)head * 300;
    const float* b1h = b1 + (size_t)head * 100;
    const float* W2h = W2 + (size_t)head * 500;

    dma16(W1h + 4 * lane,                      region);            // W1 f4 0..63
    if (lane < 11) dma16(W1h + 256 + 4 * lane, region + 256);      // W1 f4 64..74
    if (lane < 25) dma16(b1h + 4 * lane,       region + OF_B1);    // b1 25 f4
    dma16(W2h + 4 * lane,                      region + OF_W2);    // W2 f4 0..63
    if (lane < 61) dma16(W2h + 256 + 4 * lane, region + OF_W2 + 256); // W2 f4 64..124
}

// wave64 DPP reduction step: acc += dpp(acc)   (R3-verified)
template <int CTRL, int ROW_MASK>
static __device__ __forceinline__ float dpp_add_step(float acc) {
    union { float f; int i; } in, out;
    in.f = acc;
    out.i = __builtin_amdgcn_update_dpp(0, in.i, CTRL, ROW_MASK, 0xF, false);
    return acc + out.f;
}
static __device__ __forceinline__ float wave_reduce_add(float acc) {
    acc = dpp_add_step<0x111, 0xF>(acc);  // row_shr:1
    acc = dpp_add_step<0x112, 0xF>(acc);  // row_shr:2
    acc = dpp_add_step<0x114, 0xF>(acc);  // row_shr:4
    acc = dpp_add_step<0x118, 0xF>(acc);  // row_shr:8
    acc = dpp_add_step<0x142, 0xA>(acc);  // row_bcast:15 -> rows 1,3
    acc = dpp_add_step<0x143, 0xC>(acc);  // row_bcast:31 -> rows 2,3
    union { float f; int i; } v, r;
    v.f = acc;
    r.i = __builtin_amdgcn_readlane(v.i, 63);
    return r.f;
}

static __device__ __forceinline__ void compute_head(
    const float* region, int head, int lane, bool do_store,
    const float* __restrict__ x, const float* __restrict__ b2,
    float* __restrict__ out)
{
    // wave-uniform scalar-path loads for the tiny operands
    const int sh = __builtin_amdgcn_readfirstlane(head);
    const float x0 = x[sh * 3 + 0];
    const float x1 = x[sh * 3 + 1];
    const float x2 = x[sh * 3 + 2];

    const bool has2 = (lane < HID - 64);            // lanes 0..35
    const int  j2   = has2 ? (lane + 64) : (HID - 1);

    float h0, h1;
    {
        const float* r = region + 3 * lane;
        h0 = fmaxf(fmaf(r[0], x0, fmaf(r[1], x1, fmaf(r[2], x2,
                   region[OF_B1 + lane]))), 0.0f);
    }
    {
        const float* r = region + 3 * j2;
        h1 = fmaxf(fmaf(r[0], x0, fmaf(r[1], x1, fmaf(r[2], x2,
                   region[OF_B1 + j2]))), 0.0f);
        h1 = has2 ? h1 : 0.0f;
    }

    float logit[OUT];
#pragma unroll
    for (int o = 0; o < OUT; ++o) {
        float p = fmaf(region[OF_W2 + o * HID + j2], h1,
                       region[OF_W2 + o * HID + lane] * h0);
        logit[o] = wave_reduce_add(p) + b2[sh * OUT + o];
    }

    float m = -INFINITY;
#pragma unroll
    for (int o = 0; o < OUT; ++o) m = fmaxf(m, logit[o]);
    float e[OUT], s = 0.0f;
#pragma unroll
    for (int o = 0; o < OUT; ++o) { e[o] = __expf(logit[o] - m); s += e[o]; }
    const float inv = 1.0f / s;

    if (do_store && lane < OUT) {
        float v = (lane == 0) ? e[0]
                : (lane == 1) ? e[1]
                : (lane == 2) ? e[2]
                : (lane == 3) ? e[3]
                :               e[4];
        out[(size_t)head * OUT + lane] = v * inv;
    }
}

__global__ __launch_bounds__(128) void distral_kernel(
    const float* __restrict__ x,
    const float* __restrict__ W1,
    const float* __restrict__ b1,
    const float* __restrict__ W2,
    const float* __restrict__ b2,
    float* __restrict__ out)
{
    __shared__ float lds[WAVES_PER_BLOCK][2][HEAD_F];   // 14400 B

    const int lane = threadIdx.x & 63;
    const int wv   = threadIdx.x >> 6;

    // wave handles two ADJACENT heads (contiguous W1/W2 streams)
    const int base   = blockIdx.x * (2 * WAVES_PER_BLOCK) + 2 * wv;
    const bool v0    = (base     < N_HEADS);
    const bool v1    = (base + 1 < N_HEADS);
    const int headA  = v0 ? base     : 0;      // clamp keeps control flow uniform
    const int headB  = v1 ? base + 1 : headA;

    // ---- burst: 10 wide DMAs back-to-back ----
    stage_head(headA, lane, &lds[wv][0][0], W1, b1, W2);
    stage_head(headB, lane, &lds[wv][1][0], W1, b1, W2);

    // ---- drain A's 5, leave B's 5 in flight ----
    asm volatile("" ::: "memory");
    __builtin_amdgcn_s_waitcnt(0x0F75);        // vmcnt(5)
    asm volatile("" ::: "memory");
    compute_head(&lds[wv][0][0], headA, lane, v0, x, b2, out);

    // ---- drain B's 5 (A's store, issued last, may stay outstanding) ----
    asm volatile("" ::: "memory");
    __builtin_amdgcn_s_waitcnt(0x0F71);        // vmcnt(1)
    asm volatile("" ::: "memory");
    compute_head(&lds[wv][1][0], headB, lane, v1, x, b2, out);
}

extern "C" void kernel_launch(void* const* d_in, const int* in_sizes, int n_in,
                              void* d_out, int out_size, void* d_ws, size_t ws_size,
                              hipStream_t stream) {
    const float* x  = (const float*)d_in[0];
    const float* W1 = (const float*)d_in[1];
    const float* b1 = (const float*)d_in[2];
    const float* W2 = (const float*)d_in[3];
    const float* b2 = (const float*)d_in[4];
    float* out = (float*)d_out;

    const int heads_per_block = 2 * WAVES_PER_BLOCK;   // 4
    const int blocks = (N_HEADS + heads_per_block - 1) / heads_per_block;
    distral_kernel<<<blocks, 128, 0, stream>>>(x, W1, b1, W2, b2, out);
}

// Round 7
// 142.080 us; speedup vs baseline: 1.0338x; 1.0041x over previous
//
#include <hip/hip_runtime.h>
#include <math.h>

// Distral per-task MLP: 32769 heads, h = relu(W1[3->100] x + b1),
// p = softmax(W2[100->5] h + b2).  ~3.6 KB read/head, ~119 MB total.
//
// R7: copy-mubench shape — per-lane float4 register streaming.
// R1-R6 matrix: every batch-wait structure (LDS-DMA one-shot/dbuf/burst2,
// scalar-register pipeline) converges at ~36-43us (~3.4 TB/s).  The copy
// kernel reaches 6.3 TB/s with per-lane independent vector loads consumed
// incrementally.  Reproduce that shape: lane l owns hidden chunk 4l..4l+3
// (HID=100=25 chunks), so W1 (3 f4), b1 (1 f4), W2 (5 f4) are ALL dwordx4
// register loads, 9 independent per lane, no LDS, h never leaves the lane.
// Two heads per wave (32-lane halves, 25 active each); 5-step shfl_xor
// reduce per half (reduce cost proven irrelevant in R3).

#define N_HEADS 32769
#define HID     100
#define OUT     5
#define CHUNKS  25               // float4 chunks per head

__global__ __launch_bounds__(256) void distral_kernel(
    const float* __restrict__ x,
    const float* __restrict__ W1,
    const float* __restrict__ b1,
    const float* __restrict__ W2,
    const float* __restrict__ b2,
    float* __restrict__ out)
{
    const int lane = threadIdx.x & 63;
    const int half = lane >> 5;          // 0 or 1: which head this half-wave owns
    const int ll   = lane & 31;          // lane within half
    const int wv   = threadIdx.x >> 6;

    const int  hraw  = blockIdx.x * 8 + wv * 2 + half;   // 8 heads per block
    const bool valid = (hraw < N_HEADS);
    const int  head  = valid ? hraw : (N_HEADS - 1);     // clamp: loads stay legal

    const int c = (ll < CHUNKS) ? ll : (CHUNKS - 1);     // clamped chunk id
    const bool active = (ll < CHUNKS);

    const float4* W1q = (const float4*)(W1 + (size_t)head * 300);  // 16B-aligned
    const float4* b1q = (const float4*)(b1 + (size_t)head * 100);
    const float4* W2q = (const float4*)(W2 + (size_t)head * 500);

    // ---- 9 independent dwordx4 loads per lane ----
    const float4 q0 = W1q[3 * c + 0];    // W1 rows 4c..4c+3 (12 contiguous floats)
    const float4 q1 = W1q[3 * c + 1];
    const float4 q2 = W1q[3 * c + 2];
    const float4 bq = b1q[c];
    float4 w2[OUT];
#pragma unroll
    for (int o = 0; o < OUT; ++o)
        w2[o] = W2q[CHUNKS * o + c];     // W2[o][4c..4c+3]

    // tiny operands: same address across the half -> broadcast L1 hits
    const float x0 = x[head * 3 + 0];
    const float x1 = x[head * 3 + 1];
    const float x2 = x[head * 3 + 2];
    float b2v[OUT];
#pragma unroll
    for (int o = 0; o < OUT; ++o) b2v[o] = b2[head * OUT + o];

    // ---- layer 1: this lane's 4 hidden units, in-lane ----
    const float h0 = fmaxf(fmaf(q0.x, x0, fmaf(q0.y, x1, fmaf(q0.z, x2, bq.x))), 0.f);
    const float h1 = fmaxf(fmaf(q0.w, x0, fmaf(q1.x, x1, fmaf(q1.y, x2, bq.y))), 0.f);
    const float h2 = fmaxf(fmaf(q1.z, x0, fmaf(q1.w, x1, fmaf(q2.x, x2, bq.z))), 0.f);
    const float h3 = fmaxf(fmaf(q2.y, x0, fmaf(q2.z, x1, fmaf(q2.w, x2, bq.w))), 0.f);

    // ---- layer 2: per-lane dot4, then 32-lane-half butterfly ----
    float logit[OUT];
#pragma unroll
    for (int o = 0; o < OUT; ++o) {
        float p = fmaf(h0, w2[o].x, fmaf(h1, w2[o].y,
                  fmaf(h2, w2[o].z, h3 * w2[o].w)));
        p = active ? p : 0.0f;           // lanes 25..31 contribute nothing
#pragma unroll
        for (int m = 16; m > 0; m >>= 1)
            p += __shfl_xor(p, m, 64);   // masks <32: stays within the half
        logit[o] = p + b2v[o];
    }

    // ---- softmax (uniform within each half) ----
    float mx = -INFINITY;
#pragma unroll
    for (int o = 0; o < OUT; ++o) mx = fmaxf(mx, logit[o]);
    float e[OUT], s = 0.0f;
#pragma unroll
    for (int o = 0; o < OUT; ++o) { e[o] = __expf(logit[o] - mx); s += e[o]; }
    const float inv = 1.0f / s;

    if (valid && ll < OUT) {
        float v = (ll == 0) ? e[0]
                : (ll == 1) ? e[1]
                : (ll == 2) ? e[2]
                : (ll == 3) ? e[3]
                :             e[4];
        out[(size_t)head * OUT + ll] = v * inv;
    }
}

extern "C" void kernel_launch(void* const* d_in, const int* in_sizes, int n_in,
                              void* d_out, int out_size, void* d_ws, size_t ws_size,
                              hipStream_t stream) {
    const float* x  = (const float*)d_in[0];
    const float* W1 = (const float*)d_in[1];
    const float* b1 = (const float*)d_in[2];
    const float* W2 = (const float*)d_in[3];
    const float* b2 = (const float*)d_in[4];
    float* out = (float*)d_out;

    const int heads_per_block = 8;       // 4 waves x 2 heads
    const int blocks = (N_HEADS + heads_per_block - 1) / heads_per_block;
    distral_kernel<<<blocks, 256, 0, stream>>>(x, W1, b1, W2, b2, out);
}

// Round 8
// 141.896 us; speedup vs baseline: 1.0351x; 1.0013x over previous
//
#include <hip/hip_runtime.h>
#include <math.h>

// Distral per-task MLP: 32769 heads, h = relu(W1[3->100] x + b1),
// p = softmax(W2[100->5] h + b2).  ~3.6 KB read/head, ~119 MB total.
//
// R8: XCD-partitioned head ordering.  R1-R7: six structurally distinct
// kernels (scalar/DMA/dbuf/burst2/register-f4) all cap at ~3.4 TB/s;
// per-wave structure is irrelevant.  Last untested lever: device-level
// spatial ordering.  Consecutive blocks round-robin across 8 XCDs, so
// previously every XCD scattered over the full 119 MB.  Now the head
// space is split into 8 contiguous ~15MB partitions and blockIdx is
// swizzled (p = bid & 7) so each XCD streams its own contiguous window
// -- the property the 6.5 TB/s fill/copy kernels have and we never did.
// Compute structure = R7 (register float4, lane owns hidden chunk 4c,
// two heads per wave in 32-lane halves).

#define N_HEADS 32769
#define HID     100
#define OUT     5
#define CHUNKS  25               // float4 chunks per head
#define PART    4100             // heads per XCD partition (8*4100 >= N_HEADS)
#define BLK_PER_PART 513         // ceil(4100/8 heads-per-block)

__global__ __launch_bounds__(256) void distral_kernel(
    const float* __restrict__ x,
    const float* __restrict__ W1,
    const float* __restrict__ b1,
    const float* __restrict__ W2,
    const float* __restrict__ b2,
    float* __restrict__ out)
{
    const int lane = threadIdx.x & 63;
    const int half = lane >> 5;          // 0/1: which head this half-wave owns
    const int ll   = lane & 31;
    const int wv   = threadIdx.x >> 6;

    // XCD swizzle: partition p = bid & 7 lands round-robin on XCD p,
    // and reads only heads [p*PART, p*PART+4100) -- contiguous ~15 MB.
    const int p    = blockIdx.x & 7;
    const int i    = blockIdx.x >> 3;            // 0..BLK_PER_PART-1
    const int slot = i * 8 + wv * 2 + half;      // head index within partition
    const int hraw = p * PART + slot;
    const bool valid = (slot < PART) && (hraw < N_HEADS);
    const int  head  = valid ? hraw : (N_HEADS - 1);   // clamp keeps loads legal

    const int c = (ll < CHUNKS) ? ll : (CHUNKS - 1);
    const bool active = (ll < CHUNKS);

    const float4* W1q = (const float4*)(W1 + (size_t)head * 300);  // 16B-aligned
    const float4* b1q = (const float4*)(b1 + (size_t)head * 100);
    const float4* W2q = (const float4*)(W2 + (size_t)head * 500);

    // ---- 9 independent dwordx4 loads per lane (R7-verified) ----
    const float4 q0 = W1q[3 * c + 0];    // W1 rows 4c..4c+3
    const float4 q1 = W1q[3 * c + 1];
    const float4 q2 = W1q[3 * c + 2];
    const float4 bq = b1q[c];
    float4 w2[OUT];
#pragma unroll
    for (int o = 0; o < OUT; ++o)
        w2[o] = W2q[CHUNKS * o + c];     // W2[o][4c..4c+3]

    const float x0 = x[head * 3 + 0];
    const float x1 = x[head * 3 + 1];
    const float x2 = x[head * 3 + 2];
    float b2v[OUT];
#pragma unroll
    for (int o = 0; o < OUT; ++o) b2v[o] = b2[head * OUT + o];

    // ---- layer 1: this lane's 4 hidden units, in-lane ----
    const float h0 = fmaxf(fmaf(q0.x, x0, fmaf(q0.y, x1, fmaf(q0.z, x2, bq.x))), 0.f);
    const float h1 = fmaxf(fmaf(q0.w, x0, fmaf(q1.x, x1, fmaf(q1.y, x2, bq.y))), 0.f);
    const float h2 = fmaxf(fmaf(q1.z, x0, fmaf(q1.w, x1, fmaf(q2.x, x2, bq.z))), 0.f);
    const float h3 = fmaxf(fmaf(q2.y, x0, fmaf(q2.z, x1, fmaf(q2.w, x2, bq.w))), 0.f);

    // ---- layer 2: per-lane dot4 + 32-half butterfly ----
    float logit[OUT];
#pragma unroll
    for (int o = 0; o < OUT; ++o) {
        float pt = fmaf(h0, w2[o].x, fmaf(h1, w2[o].y,
                   fmaf(h2, w2[o].z, h3 * w2[o].w)));
        pt = active ? pt : 0.0f;
#pragma unroll
        for (int m = 16; m > 0; m >>= 1)
            pt += __shfl_xor(pt, m, 64); // masks <32: stays within the half
        logit[o] = pt + b2v[o];
    }

    // ---- softmax (uniform within each half) ----
    float mx = -INFINITY;
#pragma unroll
    for (int o = 0; o < OUT; ++o) mx = fmaxf(mx, logit[o]);
    float e[OUT], s = 0.0f;
#pragma unroll
    for (int o = 0; o < OUT; ++o) { e[o] = __expf(logit[o] - mx); s += e[o]; }
    const float inv = 1.0f / s;

    if (valid && ll < OUT) {
        float v = (ll == 0) ? e[0]
                : (ll == 1) ? e[1]
                : (ll == 2) ? e[2]
                : (ll == 3) ? e[3]
                :             e[4];
        out[(size_t)head * OUT + ll] = v * inv;
    }
}

extern "C" void kernel_launch(void* const* d_in, const int* in_sizes, int n_in,
                              void* d_out, int out_size, void* d_ws, size_t ws_size,
                              hipStream_t stream) {
    const float* x  = (const float*)d_in[0];
    const float* W1 = (const float*)d_in[1];
    const float* b1 = (const float*)d_in[2];
    const float* W2 = (const float*)d_in[3];
    const float* b2 = (const float*)d_in[4];
    float* out = (float*)d_out;

    distral_kernel<<<8 * BLK_PER_PART, 256, 0, stream>>>(x, W1, b1, W2, b2, out);
}